// Round 1
// baseline (356.492 us; speedup 1.0000x reference)
//
#include <hip/hip_runtime.h>

#define N_ 64
#define C_ 64
#define T_ 256
#define V_ 25
#define R_ 8
#define O_ 64
constexpr int TV = T_ * V_;          // 6400
constexpr float INV_T = 1.0f / T_;

// -------- Kernel 1: xm[n][c][v] = mean_t x[n][c][t][v] --------
__global__ __launch_bounds__(256) void k_mean(const float* __restrict__ x,
                                              float* __restrict__ xm) {
    __shared__ float sums[V_];
    const int bid = blockIdx.x;           // n*C + c
    const int tid = threadIdx.x;
    if (tid < V_) sums[tid] = 0.f;
    __syncthreads();
    const float* xp = x + (size_t)bid * TV;
    #pragma unroll
    for (int k = 0; k < TV / 256; ++k) {  // 25 iterations, fully covers 6400
        int idx = k * 256 + tid;
        atomicAdd(&sums[idx % V_], xp[idx]);
    }
    __syncthreads();
    if (tid < V_) xm[(size_t)bid * V_ + tid] = sums[tid] * INV_T;
}

// -------- Kernel 2: d[n][o][u][v] = sum_r w4[o,r]*tanh(x1[n,r,u]-x2[n,r,v]) + b4[o] + A[u,v]
__global__ __launch_bounds__(256) void k_dmat(const float* __restrict__ xm,
                                              const float* __restrict__ A,
                                              const float* __restrict__ w1,
                                              const float* __restrict__ b1,
                                              const float* __restrict__ w2,
                                              const float* __restrict__ b2,
                                              const float* __restrict__ w4,
                                              const float* __restrict__ b4,
                                              float* __restrict__ d) {
    __shared__ float xms[C_][V_];
    __shared__ float x1s[R_][V_];
    __shared__ float x2s[R_][V_];
    const int n = blockIdx.x;
    const int tid = threadIdx.x;

    for (int i = tid; i < C_ * V_; i += 256)
        xms[i / V_][i % V_] = xm[(size_t)n * C_ * V_ + i];
    __syncthreads();

    for (int i = tid; i < 2 * R_ * V_; i += 256) {
        const int j = i % (R_ * V_);
        const int r = j / V_, v = j % V_;
        const bool first = (i < R_ * V_);
        const float* w = first ? w1 : w2;
        float acc = first ? b1[r] : b2[r];
        #pragma unroll
        for (int c = 0; c < C_; ++c) acc += w[r * C_ + c] * xms[c][v];
        if (first) x1s[r][v] = acc;
        else       x2s[r][v] = acc;
    }
    __syncthreads();

    for (int p = tid; p < V_ * V_; p += 256) {
        const int u = p / V_, v = p % V_;
        float adjr[R_];
        #pragma unroll
        for (int r = 0; r < R_; ++r) adjr[r] = tanhf(x1s[r][u] - x2s[r][v]);
        const float a = A[u * V_ + v];
        for (int o = 0; o < O_; ++o) {
            float acc = b4[o];
            #pragma unroll
            for (int r = 0; r < R_; ++r) acc = fmaf(w4[o * R_ + r], adjr[r], acc);
            d[(((size_t)n * O_ + o) * V_ + u) * V_ + v] = acc + a;  // ALPHA == 1
        }
    }
}

// -------- Kernel 3: x3[n][o][tu] = sum_c w3[o,c]*x[n,c,tu] + b3[o]  (written to d_out)
__global__ __launch_bounds__(256) void k_x3(const float* __restrict__ x,
                                            const float* __restrict__ w3,
                                            const float* __restrict__ b3,
                                            float* __restrict__ x3) {
    const int n = blockIdx.y;
    const int tu = blockIdx.x * 256 + threadIdx.x;
    const float* xp = x + (size_t)n * C_ * TV + tu;
    float xcol[C_];
    #pragma unroll
    for (int c = 0; c < C_; ++c) xcol[c] = xp[(size_t)c * TV];  // coalesced across lanes
    float* op = x3 + (size_t)n * O_ * TV + tu;
    for (int o = 0; o < O_; ++o) {
        float acc = b3[o];                 // uniform -> scalar load
        #pragma unroll
        for (int c = 0; c < C_; ++c)
            acc = fmaf(w3[o * C_ + c], xcol[c], acc);  // w3 uniform -> s_load operand
        op[(size_t)o * TV] = acc;          // coalesced store
    }
}

// -------- Kernel 4 (in-place over d_out): out[t][v] = sum_u x3[t][u]*d[u][v] per (n,o)
__global__ __launch_bounds__(256) void k_out(const float* __restrict__ dmat,
                                             float* __restrict__ io) {
    __shared__ float xt[TV];              // 25.6 KB
    const int bid = blockIdx.x;           // n*O + o
    const int tid = threadIdx.x;
    float* base = io + (size_t)bid * TV;
    #pragma unroll
    for (int k = 0; k < TV / 256; ++k)
        xt[k * 256 + tid] = base[k * 256 + tid];   // coalesced stage
    __syncthreads();
    const float* dm = dmat + (size_t)bid * V_ * V_;
    float row[V_];
    #pragma unroll
    for (int u = 0; u < V_; ++u) row[u] = xt[tid * V_ + u];  // stride-25: 2-way max, free
    #pragma unroll
    for (int v = 0; v < V_; ++v) {
        float acc = 0.f;
        #pragma unroll
        for (int u = 0; u < V_; ++u)
            acc = fmaf(row[u], dm[u * V_ + v], acc);  // dm uniform -> scalar loads
        base[(size_t)tid * V_ + v] = acc;
    }
}

extern "C" void kernel_launch(void* const* d_in, const int* in_sizes, int n_in,
                              void* d_out, int out_size, void* d_ws, size_t ws_size,
                              hipStream_t stream) {
    const float* x  = (const float*)d_in[0];
    const float* A  = (const float*)d_in[1];
    const float* w1 = (const float*)d_in[2];
    const float* b1 = (const float*)d_in[3];
    const float* w2 = (const float*)d_in[4];
    const float* b2 = (const float*)d_in[5];
    const float* w3 = (const float*)d_in[6];
    const float* b3 = (const float*)d_in[7];
    const float* w4 = (const float*)d_in[8];
    const float* b4 = (const float*)d_in[9];

    float* out = (float*)d_out;
    float* xm  = (float*)d_ws;                 // N*C*V floats   (0.41 MB)
    float* dm  = xm + (size_t)N_ * C_ * V_;    // N*O*V*V floats (10.24 MB)

    k_mean<<<N_ * C_, 256, 0, stream>>>(x, xm);
    k_dmat<<<N_, 256, 0, stream>>>(xm, A, w1, b1, w2, b2, w4, b4, dm);
    k_x3<<<dim3(TV / 256, N_), 256, 0, stream>>>(x, w3, b3, out);
    k_out<<<N_ * O_, 256, 0, stream>>>(dm, out);
}

// Round 2
// 148.419 us; speedup vs baseline: 2.4019x; 2.4019x over previous
//
#include <hip/hip_runtime.h>

#define N_ 64
#define C_ 64
#define T_ 256
#define V_ 25
#define R_ 8
#define O_ 64
constexpr int TV = T_ * V_;          // 6400
constexpr float INV_T = 1.0f / T_;

// -------- Kernel 1: xm[n][c][v] = mean_t x[n][c][t][v] --------
// 200 active threads: vid = tid%25, seg = tid/25 (8 segments x 32 t each).
__global__ __launch_bounds__(256) void k_mean(const float* __restrict__ x,
                                              float* __restrict__ xm) {
    __shared__ float part[8 * V_];        // addr == tid for active threads -> conflict-free
    const int bid = blockIdx.x;           // n*C + c
    const int tid = threadIdx.x;
    const float* xp = x + (size_t)bid * TV;
    if (tid < 200) {
        const int vid = tid % V_;
        const int seg = tid / V_;
        float s = 0.f;
        const float* p = xp + seg * 32 * V_ + vid;
        #pragma unroll
        for (int j = 0; j < 32; ++j) s += p[j * V_];
        part[tid] = s;
    }
    __syncthreads();
    if (tid < V_) {
        float s = 0.f;
        #pragma unroll
        for (int k = 0; k < 8; ++k) s += part[k * V_ + tid];
        xm[(size_t)bid * V_ + tid] = s * INV_T;
    }
}

// -------- Kernel 2: d[n][o][u][v] = sum_r w4[o,r]*tanh(x1[n,r,u]-x2[n,r,v]) + b4[o] + A[u,v]
__global__ __launch_bounds__(256) void k_dmat(const float* __restrict__ xm,
                                              const float* __restrict__ A,
                                              const float* __restrict__ w1,
                                              const float* __restrict__ b1,
                                              const float* __restrict__ w2,
                                              const float* __restrict__ b2,
                                              const float* __restrict__ w4,
                                              const float* __restrict__ b4,
                                              float* __restrict__ d) {
    __shared__ float xms[C_][V_];
    __shared__ float x1s[R_][V_];
    __shared__ float x2s[R_][V_];
    const int n = blockIdx.x;
    const int og = blockIdx.y * 16;       // 16 o's per block
    const int tid = threadIdx.x;

    for (int i = tid; i < C_ * V_; i += 256)
        xms[i / V_][i % V_] = xm[(size_t)n * C_ * V_ + i];
    __syncthreads();

    for (int i = tid; i < 2 * R_ * V_; i += 256) {
        const int j = i % (R_ * V_);
        const int r = j / V_, v = j % V_;
        const bool first = (i < R_ * V_);
        const float* w = first ? w1 : w2;
        float acc = first ? b1[r] : b2[r];
        #pragma unroll
        for (int c = 0; c < C_; ++c) acc += w[r * C_ + c] * xms[c][v];
        if (first) x1s[r][v] = acc;
        else       x2s[r][v] = acc;
    }
    __syncthreads();

    for (int p = tid; p < V_ * V_; p += 256) {
        const int u = p / V_, v = p % V_;
        float adjr[R_];
        #pragma unroll
        for (int r = 0; r < R_; ++r) adjr[r] = tanhf(x1s[r][u] - x2s[r][v]);
        const float a = A[u * V_ + v];
        #pragma unroll
        for (int oo = 0; oo < 16; ++oo) {
            const int o = og + oo;
            float acc = b4[o];
            #pragma unroll
            for (int r = 0; r < R_; ++r) acc = fmaf(w4[o * R_ + r], adjr[r], acc);
            d[(((size_t)n * O_ + o) * V_ + u) * V_ + v] = acc + a;  // ALPHA == 1
        }
    }
}

// -------- Kernel 3: x3[n][o][tu] = sum_c w3[o,c]*x[n,c,tu] + b3[o]  (written to d_out)
// 8 o-accumulators -> 8 independent FMA chains (was 1 -> latency-bound).
__global__ __launch_bounds__(256) void k_x3(const float* __restrict__ x,
                                            const float* __restrict__ w3,
                                            const float* __restrict__ b3,
                                            float* __restrict__ x3) {
    const int n = blockIdx.y;
    const int tu = blockIdx.x * 256 + threadIdx.x;
    const float* xp = x + (size_t)n * C_ * TV + tu;
    float xcol[C_];
    #pragma unroll
    for (int c = 0; c < C_; ++c) xcol[c] = xp[(size_t)c * TV];  // coalesced
    float* op = x3 + (size_t)n * O_ * TV + tu;
    #pragma unroll 1
    for (int ot = 0; ot < O_ / 8; ++ot) {
        float acc[8];
        #pragma unroll
        for (int oo = 0; oo < 8; ++oo) acc[oo] = b3[ot * 8 + oo];
        #pragma unroll
        for (int c = 0; c < C_; ++c) {
            #pragma unroll
            for (int oo = 0; oo < 8; ++oo)
                acc[oo] = fmaf(w3[(ot * 8 + oo) * C_ + c], xcol[c], acc[oo]);
        }
        #pragma unroll
        for (int oo = 0; oo < 8; ++oo)
            op[(size_t)(ot * 8 + oo) * TV] = acc[oo];
    }
}

// -------- Kernel 4 (in-place over d_out): out[t][v] = sum_u x3[t][u]*d[u][v] per (n,o)
// thread == t; 25 independent acc chains; stores staged via LDS for coalescing.
__global__ __launch_bounds__(256) void k_out(const float* __restrict__ dmat,
                                             float* __restrict__ io) {
    __shared__ float xt[TV];              // 25.6 KB
    const int bid = blockIdx.x;           // n*O + o
    const int tid = threadIdx.x;
    float* base = io + (size_t)bid * TV;
    #pragma unroll
    for (int k = 0; k < TV / 256; ++k)
        xt[k * 256 + tid] = base[k * 256 + tid];   // coalesced stage
    __syncthreads();
    float row[V_];
    #pragma unroll
    for (int u = 0; u < V_; ++u) row[u] = xt[tid * V_ + u];  // 2-way conflict: free
    const float* dm = dmat + (size_t)bid * V_ * V_;
    float acc[V_];
    #pragma unroll
    for (int v = 0; v < V_; ++v) acc[v] = 0.f;
    #pragma unroll
    for (int u = 0; u < V_; ++u) {
        #pragma unroll
        for (int v = 0; v < V_; ++v)
            acc[v] = fmaf(row[u], dm[u * V_ + v], acc[v]);  // dm uniform -> scalar loads
    }
    __syncthreads();                      // done reading xt
    #pragma unroll
    for (int v = 0; v < V_; ++v) xt[tid * V_ + v] = acc[v];
    __syncthreads();
    #pragma unroll
    for (int k = 0; k < TV / 256; ++k)
        base[k * 256 + tid] = xt[k * 256 + tid];   // coalesced store
}

extern "C" void kernel_launch(void* const* d_in, const int* in_sizes, int n_in,
                              void* d_out, int out_size, void* d_ws, size_t ws_size,
                              hipStream_t stream) {
    const float* x  = (const float*)d_in[0];
    const float* A  = (const float*)d_in[1];
    const float* w1 = (const float*)d_in[2];
    const float* b1 = (const float*)d_in[3];
    const float* w2 = (const float*)d_in[4];
    const float* b2 = (const float*)d_in[5];
    const float* w3 = (const float*)d_in[6];
    const float* b3 = (const float*)d_in[7];
    const float* w4 = (const float*)d_in[8];
    const float* b4 = (const float*)d_in[9];

    float* out = (float*)d_out;
    float* xm  = (float*)d_ws;                 // N*C*V floats   (0.41 MB)
    float* dm  = xm + (size_t)N_ * C_ * V_;    // N*O*V*V floats (10.24 MB)

    k_mean<<<N_ * C_, 256, 0, stream>>>(x, xm);
    k_dmat<<<dim3(N_, 4), 256, 0, stream>>>(xm, A, w1, b1, w2, b2, w4, b4, dm);
    k_x3<<<dim3(TV / 256, N_), 256, 0, stream>>>(x, w3, b3, out);
    k_out<<<N_ * O_, 256, 0, stream>>>(dm, out);
}